// Round 1
// baseline (290.247 us; speedup 1.0000x reference)
//
#include <hip/hip_runtime.h>
#include <hip/hip_bf16.h>
#include <stdint.h>

typedef short bf16x8 __attribute__((ext_vector_type(8)));
typedef float f32x4  __attribute__((ext_vector_type(4)));
typedef unsigned short u16;
typedef unsigned int   u32;

#define BATCH 4
#define PTOT  4096   // H*W
#define CINT  128    // inter channels
// (1/sqrt(128)) * log2(e): fold QK scale + exp2 base change into theta
#define QK_SCALE 0.12751744f

__device__ __forceinline__ u32 pk_bf16(float a, float b) {
  u32 r;
  asm("v_cvt_pk_bf16_f32 %0, %1, %2" : "=v"(r) : "v"(a), "v"(b));
  return r;
}
__device__ __forceinline__ u16 f2bf(float x) { return (u16)pk_bf16(x, x); }

__device__ __forceinline__ f32x4 mfma16(bf16x8 a, bf16x8 b, f32x4 c) {
  return __builtin_amdgcn_mfma_f32_16x16x32_bf16(a, b, c, 0, 0, 0);
}

// ---------------- fp32 -> bf16 weight conversion ----------------
__global__ void k_cvt(const float* __restrict__ s, u16* __restrict__ d, int n) {
  int i = (blockIdx.x * 256 + threadIdx.x) * 4;
  if (i >= n) return;
  float4 v = *(const float4*)(s + i);
  *(uint2*)(d + i) = make_uint2(pk_bf16(v.x, v.y), pk_bf16(v.z, v.w));
}

// ---------------- projection -> pixel-major [B][p][c'] ----------------
// O[b][p][c'] = (sum_c X[b][c][p] * W[c'][c] + bias[c']) * scale   (bf16 out)
__global__ void k_proj_pix(const float* __restrict__ X, const u16* __restrict__ W,
                           const float* __restrict__ bias, u16* __restrict__ O,
                           int Cin, float scale) {
  const int b = blockIdx.y, p0 = blockIdx.x * 64;
  const int t = threadIdx.x, lane = t & 63, w = t >> 6;
  const int m_ = lane & 15, h = lane >> 4;
  __shared__ __align__(16) u16 At[64][40];    // x^T tile [p][c], padded row 80B
  __shared__ __align__(16) u16 Wl[128][40];   // W tile   [c'][c]
  const float* xb = X + (size_t)b * Cin * PTOT;
  f32x4 acc[4][2];
#pragma unroll
  for (int i = 0; i < 4; i++) { acc[i][0] = (f32x4)0.0f; acc[i][1] = (f32x4)0.0f; }
  const int p = t & 63, cg = t >> 6;          // transpose-stage mapping
  const int wrow = t >> 1, whalf = t & 1;     // W-stage mapping
  for (int k0 = 0; k0 < Cin; k0 += 32) {
    __syncthreads();
    { // stage x[k0..k0+31][p0..p0+63] fp32 -> At[p][c] bf16 (transpose)
      const float* sx = xb + (size_t)(k0 + 8 * cg) * PTOT + p0 + p;
      float v0 = sx[0],        v1 = sx[PTOT],   v2 = sx[2*PTOT], v3 = sx[3*PTOT];
      float v4 = sx[4*PTOT],   v5 = sx[5*PTOT], v6 = sx[6*PTOT], v7 = sx[7*PTOT];
      *(uint2*)&At[p][8*cg]     = make_uint2(pk_bf16(v0,v1), pk_bf16(v2,v3));
      *(uint2*)&At[p][8*cg + 4] = make_uint2(pk_bf16(v4,v5), pk_bf16(v6,v7));
    }
    { // stage W[c'][k0..k0+31] bf16
      const u16* sw = W + (size_t)wrow * Cin + k0 + whalf * 16;
      uint4 a = *(const uint4*)sw, c = *(const uint4*)(sw + 8);
      *(uint4*)&Wl[wrow][whalf*16]     = a;
      *(uint4*)&Wl[wrow][whalf*16 + 8] = c;
    }
    __syncthreads();
    bf16x8 bf0 = *(const bf16x8*)&Wl[w*32 + m_][8*h];
    bf16x8 bf1 = *(const bf16x8*)&Wl[w*32 + 16 + m_][8*h];
#pragma unroll
    for (int mb = 0; mb < 4; mb++) {
      bf16x8 af = *(const bf16x8*)&At[mb*16 + m_][8*h];
      acc[mb][0] = mfma16(af, bf0, acc[mb][0]);
      acc[mb][1] = mfma16(af, bf1, acc[mb][1]);
    }
  }
  u16* ob = O + (size_t)b * PTOT * CINT;
#pragma unroll
  for (int mb = 0; mb < 4; mb++)
#pragma unroll
    for (int nb = 0; nb < 2; nb++) {
      int c = w*32 + nb*16 + m_;
      float bv = bias[c];
#pragma unroll
      for (int r = 0; r < 4; r++) {
        int pp = p0 + mb*16 + 4*h + r;
        ob[(size_t)pp * CINT + c] = f2bf((acc[mb][nb][r] + bv) * scale);
      }
    }
}

// ---------------- projection -> channel-major [B][c'][p] (for V=g) ----------------
__global__ void k_proj_ch(const float* __restrict__ X, const u16* __restrict__ W,
                          const float* __restrict__ bias, u16* __restrict__ O) {
  const int Cin = 512;
  const int b = blockIdx.y, p0 = blockIdx.x * 64;
  const int t = threadIdx.x, lane = t & 63, w = t >> 6;
  const int m_ = lane & 15, h = lane >> 4;
  __shared__ __align__(16) u16 Wl[128][40];
  __shared__ __align__(16) u16 Bt[64][40];
  const float* xb = X + (size_t)b * Cin * PTOT;
  f32x4 acc[2][4];
#pragma unroll
  for (int i = 0; i < 2; i++)
#pragma unroll
    for (int j = 0; j < 4; j++) acc[i][j] = (f32x4)0.0f;
  const int p = t & 63, cg = t >> 6;
  const int wrow = t >> 1, whalf = t & 1;
  for (int k0 = 0; k0 < Cin; k0 += 32) {
    __syncthreads();
    {
      const u16* sw = W + (size_t)wrow * Cin + k0 + whalf * 16;
      uint4 a = *(const uint4*)sw, c = *(const uint4*)(sw + 8);
      *(uint4*)&Wl[wrow][whalf*16]     = a;
      *(uint4*)&Wl[wrow][whalf*16 + 8] = c;
    }
    {
      const float* sx = xb + (size_t)(k0 + 8 * cg) * PTOT + p0 + p;
      float v0 = sx[0],      v1 = sx[PTOT],   v2 = sx[2*PTOT], v3 = sx[3*PTOT];
      float v4 = sx[4*PTOT], v5 = sx[5*PTOT], v6 = sx[6*PTOT], v7 = sx[7*PTOT];
      *(uint2*)&Bt[p][8*cg]     = make_uint2(pk_bf16(v0,v1), pk_bf16(v2,v3));
      *(uint2*)&Bt[p][8*cg + 4] = make_uint2(pk_bf16(v4,v5), pk_bf16(v6,v7));
    }
    __syncthreads();
    bf16x8 bfr[4];
#pragma unroll
    for (int nb = 0; nb < 4; nb++) bfr[nb] = *(const bf16x8*)&Bt[nb*16 + m_][8*h];
#pragma unroll
    for (int mb = 0; mb < 2; mb++) {
      bf16x8 af = *(const bf16x8*)&Wl[w*32 + mb*16 + m_][8*h];
#pragma unroll
      for (int nb = 0; nb < 4; nb++) acc[mb][nb] = mfma16(af, bfr[nb], acc[mb][nb]);
    }
  }
  u16* ob = O + (size_t)b * CINT * PTOT;
#pragma unroll
  for (int mb = 0; mb < 2; mb++)
#pragma unroll
    for (int nb = 0; nb < 4; nb++) {
      int pidx = p0 + nb*16 + m_;
#pragma unroll
      for (int r = 0; r < 4; r++) {
        int c = w*32 + mb*16 + 4*h + r;
        ob[(size_t)c * PTOT + pidx] = f2bf(acc[mb][nb][r] + bias[c]);
      }
    }
}

// ---------------- flash attention ----------------
// TH [B][4096][128] = theta (pre-scaled), PH [B][4096][128] = phi^T, G [B][128][4096] = g
// halves==2: write partial U [2][B][4096][128] fp32 + ML [2][B][4096][2]
// halves==1: write Y [B][4096][128] bf16 directly
__global__ void k_attn(const u16* __restrict__ TH, const u16* __restrict__ PH,
                       const u16* __restrict__ G, float* __restrict__ U,
                       float* __restrict__ ML, u16* __restrict__ Y, int halves) {
  const int b = blockIdx.y, q0 = blockIdx.x * 64, zz = blockIdx.z;
  const int t = threadIdx.x, lane = t & 63, w = t >> 6;
  const int m_ = lane & 15, h = lane >> 4;
  __shared__ __align__(16) u16 Kl[64][136];    // phi rows [k][c], 272B rows
  __shared__ __align__(16) u16 Vl[128][80];    // g rows   [c'][k], 160B rows
  __shared__ __align__(16) u16 Pl[4][16][80];  // per-wave P [q][k], 160B rows
  const u16* thb = TH + (size_t)b * PTOT * CINT;
  const u16* phb = PH + (size_t)b * PTOT * CINT;
  const u16* gb  = G  + (size_t)b * CINT * PTOT;
  const int q = q0 + w*16 + m_;
  bf16x8 qf[4];
  {
    const u16* qr = thb + (size_t)q * CINT + 8*h;
    qf[0] = *(const bf16x8*)(qr);
    qf[1] = *(const bf16x8*)(qr + 32);
    qf[2] = *(const bf16x8*)(qr + 64);
    qf[3] = *(const bf16x8*)(qr + 96);
  }
  f32x4 yacc[8];
#pragma unroll
  for (int i = 0; i < 8; i++) yacc[i] = (f32x4)0.0f;
  float mrun = -3.0e38f, lrun = 0.0f;
  const int niter = 64 / halves;
  const int it0 = zz * niter;
  const int krow = t >> 4, kch = t & 15;
  const int vrow = t >> 3, vch = t & 7;
  for (int it = it0; it < it0 + niter; ++it) {
    const int k0 = it * 64;
    __syncthreads();
#pragma unroll
    for (int i = 0; i < 4; i++) {
      uint4 v = *(const uint4*)(phb + (size_t)(k0 + krow + 16*i) * CINT + kch*8);
      *(uint4*)&Kl[krow + 16*i][kch*8] = v;
    }
#pragma unroll
    for (int i = 0; i < 4; i++) {
      uint4 v = *(const uint4*)(gb + (size_t)(vrow + 32*i) * PTOT + k0 + vch*8);
      *(uint4*)&Vl[vrow + 32*i][vch*8] = v;
    }
    __syncthreads();
    // S^T[k][q] = sum_c phi[k][c] * theta[q][c]  (swapped -> q is lane&15)
    f32x4 sa[4];
#pragma unroll
    for (int i = 0; i < 4; i++) sa[i] = (f32x4)0.0f;
#pragma unroll
    for (int ks = 0; ks < 4; ks++) {
#pragma unroll
      for (int mb = 0; mb < 4; mb++) {
        bf16x8 af = *(const bf16x8*)&Kl[mb*16 + m_][ks*32 + 8*h];
        sa[mb] = mfma16(af, qf[ks], sa[mb]);
      }
    }
    // online softmax over k (lane holds k = mb*16 + 4*h + r for its q)
    float tmax = -3.0e38f;
#pragma unroll
    for (int mb = 0; mb < 4; mb++)
#pragma unroll
      for (int r = 0; r < 4; r++) tmax = fmaxf(tmax, sa[mb][r]);
    tmax = fmaxf(tmax, __shfl_xor(tmax, 16));
    tmax = fmaxf(tmax, __shfl_xor(tmax, 32));
    float mnew = fmaxf(mrun, tmax);
    float f = exp2f(mrun - mnew);
    mrun = mnew;
    float ts = 0.0f;
#pragma unroll
    for (int mb = 0; mb < 4; mb++) {
      float e0 = exp2f(sa[mb][0] - mnew);
      float e1 = exp2f(sa[mb][1] - mnew);
      float e2 = exp2f(sa[mb][2] - mnew);
      float e3 = exp2f(sa[mb][3] - mnew);
      ts += (e0 + e1) + (e2 + e3);
      *(uint2*)&Pl[w][m_][mb*16 + 4*h] = make_uint2(pk_bf16(e0, e1), pk_bf16(e2, e3));
    }
    ts += __shfl_xor(ts, 16);
    ts += __shfl_xor(ts, 32);
    lrun = lrun * f + ts;
#pragma unroll
    for (int i = 0; i < 8; i++) yacc[i] *= f;
    asm volatile("s_waitcnt lgkmcnt(0)" ::: "memory");  // wave-private P ready
    // y^T[c'][q] += g[c'][k] * P[q][k]
#pragma unroll
    for (int ks = 0; ks < 2; ks++) {
      bf16x8 pb = *(const bf16x8*)&Pl[w][m_][ks*32 + 8*h];
#pragma unroll
      for (int mb = 0; mb < 8; mb++) {
        bf16x8 av = *(const bf16x8*)&Vl[mb*16 + m_][ks*32 + 8*h];
        yacc[mb] = mfma16(av, pb, yacc[mb]);
      }
    }
  }
  if (halves == 2) {
    float* ub = U + (((size_t)zz * BATCH + b) * PTOT + q) * CINT;
#pragma unroll
    for (int mb = 0; mb < 8; mb++) *(f32x4*)(ub + mb*16 + 4*h) = yacc[mb];
    if (h == 0) {
      float* mlb = ML + ((size_t)zz * BATCH + b) * PTOT * 2 + (size_t)q * 2;
      mlb[0] = mrun; mlb[1] = lrun;
    }
  } else {
    float inv = 1.0f / lrun;
    u16* yb = Y + ((size_t)b * PTOT + q) * CINT;
#pragma unroll
    for (int mb = 0; mb < 8; mb++) {
      f32x4 v = yacc[mb];
      *(uint2*)(yb + mb*16 + 4*h) =
        make_uint2(pk_bf16(v[0]*inv, v[1]*inv), pk_bf16(v[2]*inv, v[3]*inv));
    }
  }
}

// ---------------- combine two KV halves ----------------
__global__ void k_combine(const float* __restrict__ U, const float* __restrict__ ML,
                          u16* __restrict__ Y) {
  int tid = blockIdx.x * 256 + threadIdx.x;
  int c4 = (tid & 31) * 4;
  int q  = (tid >> 5) & (PTOT - 1);
  int b  = tid >> 17;
  const float* ml0 = ML + (size_t)b * PTOT * 2 + (size_t)q * 2;
  const float* ml1 = ml0 + (size_t)BATCH * PTOT * 2;
  float m0 = ml0[0], l0 = ml0[1], m1 = ml1[0], l1 = ml1[1];
  float M = fmaxf(m0, m1);
  float f0 = exp2f(m0 - M), f1 = exp2f(m1 - M);
  float inv = 1.0f / (l0*f0 + l1*f1);
  f0 *= inv; f1 *= inv;
  const float* u0 = U + ((size_t)b * PTOT + q) * CINT + c4;
  const float* u1 = u0 + (size_t)BATCH * PTOT * CINT;
  float4 a = *(const float4*)u0;
  float4 c = *(const float4*)u1;
  float y0 = a.x*f0 + c.x*f1, y1 = a.y*f0 + c.y*f1;
  float y2 = a.z*f0 + c.z*f1, y3 = a.w*f0 + c.w*f1;
  *(uint2*)(Y + ((size_t)b * PTOT + q) * CINT + c4) =
    make_uint2(pk_bf16(y0, y1), pk_bf16(y2, y3));
}

// ---------------- output projection + residual ----------------
// O[b][co][p] = Q[b][co][p] + sum_c' Wo[co][c'] * Y[b][p][c'] + bo[co]
__global__ void k_outproj(const float* __restrict__ Q, const u16* __restrict__ Wo,
                          const float* __restrict__ bo, const u16* __restrict__ Y,
                          float* __restrict__ O) {
  const int p0 = blockIdx.x * 64, chh = blockIdx.y, b = blockIdx.z;
  const int t = threadIdx.x, lane = t & 63, w = t >> 6;
  const int m_ = lane & 15, h = lane >> 4;
  __shared__ __align__(16) u16 Wl[128][136];
  __shared__ __align__(16) u16 Yl[64][136];
  {
    int row = t >> 1, cc = t & 1;
    const u16* src = Wo + (size_t)(chh*128 + row) * CINT + cc*64;
#pragma unroll
    for (int i = 0; i < 8; i++)
      *(uint4*)&Wl[row][cc*64 + i*8] = *(const uint4*)(src + i*8);
  }
  {
    int row = t >> 2, cc = t & 3;
    const u16* src = Y + ((size_t)b * PTOT + p0 + row) * CINT + cc*32;
#pragma unroll
    for (int i = 0; i < 4; i++)
      *(uint4*)&Yl[row][cc*32 + i*8] = *(const uint4*)(src + i*8);
  }
  __syncthreads();
  f32x4 acc[2][4];
#pragma unroll
  for (int i = 0; i < 2; i++)
#pragma unroll
    for (int j = 0; j < 4; j++) acc[i][j] = (f32x4)0.0f;
#pragma unroll
  for (int ks = 0; ks < 4; ks++) {
    bf16x8 bfr[4];
#pragma unroll
    for (int nb = 0; nb < 4; nb++) bfr[nb] = *(const bf16x8*)&Yl[nb*16 + m_][ks*32 + 8*h];
#pragma unroll
    for (int mb = 0; mb < 2; mb++) {
      bf16x8 af = *(const bf16x8*)&Wl[w*32 + mb*16 + m_][ks*32 + 8*h];
#pragma unroll
      for (int nb = 0; nb < 4; nb++) acc[mb][nb] = mfma16(af, bfr[nb], acc[mb][nb]);
    }
  }
  const size_t cob = (size_t)b * 256 + (size_t)chh * 128;
#pragma unroll
  for (int mb = 0; mb < 2; mb++)
#pragma unroll
    for (int nb = 0; nb < 4; nb++) {
      int pidx = p0 + nb*16 + m_;
#pragma unroll
      for (int r = 0; r < 4; r++) {
        int co = w*32 + mb*16 + 4*h + r;
        size_t idx = (cob + co) * PTOT + pidx;
        O[idx] = Q[idx] + acc[mb][nb][r] + bo[chh*128 + co];
      }
    }
}

extern "C" void kernel_launch(void* const* d_in, const int* in_sizes, int n_in,
                              void* d_out, int out_size, void* d_ws, size_t ws_size,
                              hipStream_t stream) {
  const float* q_in = (const float*)d_in[0];
  const float* ref  = (const float*)d_in[1];
  const float* Wg   = (const float*)d_in[2];
  const float* bg   = (const float*)d_in[3];
  const float* Wt   = (const float*)d_in[4];
  const float* bt   = (const float*)d_in[5];
  const float* Wp   = (const float*)d_in[6];
  const float* bp   = (const float*)d_in[7];
  const float* Wo   = (const float*)d_in[8];
  const float* bo   = (const float*)d_in[9];
  float* out = (float*)d_out;
  char* ws = (char*)d_ws;

  // workspace layout (bytes)
  u16* WtB = (u16*)(ws + 0);         // 128*256*2   = 65536
  u16* WpB = (u16*)(ws + 65536);     // 128*512*2   = 131072
  u16* WgB = (u16*)(ws + 196608);    // 128*512*2   = 131072
  u16* WoB = (u16*)(ws + 327680);    // 256*128*2   = 65536
  u16* TH  = (u16*)(ws + 393216);    // 4*4096*128*2 = 4 MiB
  u16* PH  = (u16*)(ws + 4587520);
  u16* G   = (u16*)(ws + 8781824);
  float* U = (float*)(ws + 12976128);   // 2*4*4096*128*4 = 16 MiB (halves==2)
  float* ML= (float*)(ws + 29753344);   // 2*4*4096*2*4
  const size_t NEED2 = 30015488;
  int halves = (ws_size >= NEED2) ? 2 : 1;
  // halves==2: Y reuses the TH slot (theta dead after k_attn).
  // halves==1: Y placed right after G (total need ~17.2 MB).
  u16* Y = (halves == 2) ? TH : (u16*)(ws + 12976128);

  k_cvt<<<32, 256, 0, stream>>>(Wt, WtB, 32768);
  k_cvt<<<64, 256, 0, stream>>>(Wp, WpB, 65536);
  k_cvt<<<64, 256, 0, stream>>>(Wg, WgB, 65536);
  k_cvt<<<32, 256, 0, stream>>>(Wo, WoB, 32768);

  dim3 gp(64, BATCH);
  k_proj_pix<<<gp, 256, 0, stream>>>(q_in, WtB, bt, TH, 256, QK_SCALE);
  k_proj_pix<<<gp, 256, 0, stream>>>(ref,  WpB, bp, PH, 512, 1.0f);
  k_proj_ch <<<gp, 256, 0, stream>>>(ref,  WgB, bg, G);

  dim3 ga(64, BATCH, halves);
  k_attn<<<ga, 256, 0, stream>>>(TH, PH, G, U, ML, Y, halves);
  if (halves == 2) k_combine<<<2048, 256, 0, stream>>>(U, ML, Y);

  dim3 go(64, 2, BATCH);
  k_outproj<<<go, 256, 0, stream>>>(q_in, WoB, bo, Y, out);
}